// Round 5
// baseline (311.981 us; speedup 1.0000x reference)
//
#include <hip/hip_runtime.h>
#include <math.h>

#define N_ATOMS 20000
#define N_EDGES 200000
#define CH 64
#define NB 8
#define NK 11
#define COPY_BLOCKS 12500   // 200000*64/4 float4 / (64 threads * 4 each)

// ---------------------------------------------------------------
// Kernel 1: histogram of idx_i
__global__ __launch_bounds__(256) void hist_kernel(
    const int* __restrict__ idx_i, int* __restrict__ counts)
{
    int e = blockIdx.x * blockDim.x + threadIdx.x;
    if (e >= N_EDGES) return;
    atomicAdd(&counts[idx_i[e]], 1);
}

// ---------------------------------------------------------------
// Kernel 2: exclusive scan (single 1024-thread block)
__global__ __launch_bounds__(1024) void scan_kernel(
    const int* __restrict__ counts, int* __restrict__ offsets,
    int* __restrict__ cursor)
{
    __shared__ int part[1024];
    const int CHUNK = 20;  // 1024*20 = 20480 >= 20000
    int t = threadIdx.x;
    int beg = t * CHUNK;
    int s = 0;
    for (int k = 0; k < CHUNK; ++k) {
        int idx = beg + k;
        if (idx < N_ATOMS) s += counts[idx];
    }
    part[t] = s;
    __syncthreads();
    for (int off = 1; off < 1024; off <<= 1) {
        int v = (t >= off) ? part[t - off] : 0;
        __syncthreads();
        part[t] += v;
        __syncthreads();
    }
    int run = part[t] - s;
    for (int k = 0; k < CHUNK; ++k) {
        int idx = beg + k;
        if (idx < N_ATOMS) {
            offsets[idx] = run;
            cursor[idx] = run;
            run += counts[idx];
        }
    }
    if (t == 0) offsets[N_ATOMS] = N_EDGES;
}

// ---------------------------------------------------------------
// Kernel 3: scatter into CSR order, computing geometry on the fly
// ge4[p][0..2] = {rh, rbf0..7, pad}; jlist[p] = idx_j[e]
__global__ __launch_bounds__(256) void scatter_geom_kernel(
    const float* __restrict__ rij, const int* __restrict__ idx_i,
    const int* __restrict__ idx_j, int* __restrict__ cursor,
    int* __restrict__ jlist, float4* __restrict__ ge4)
{
    int e = blockIdx.x * blockDim.x + threadIdx.x;
    if (e >= N_EDGES) return;

    float rx = rij[e * 3 + 0];
    float ry = rij[e * 3 + 1];
    float rz = rij[e * 3 + 2];
    float d = sqrtf(rx * rx + ry * ry + rz * rz);
    float inv = 1.0f / (d + 1e-12f);

    float dc = fminf(d, 5.0f);
    float fcut = 0.5f * (cosf(3.14159265358979323846f * dc * 0.2f) + 1.0f);

    float rbf[NB];
#pragma unroll
    for (int b = 0; b < NB; ++b) {
        float mu = (5.0f / 7.0f) * (float)b;
        float t = d - mu;
        rbf[b] = expf(-2.0f * t * t) * fcut;
    }

    int p = atomicAdd(&cursor[idx_i[e]], 1);
    jlist[p] = idx_j[e];
    ge4[p * 3 + 0] = make_float4(rx * inv, ry * inv, rz * inv, rbf[0]);
    ge4[p * 3 + 1] = make_float4(rbf[1], rbf[2], rbf[3], rbf[4]);
    ge4[p * 3 + 2] = make_float4(rbf[5], rbf[6], rbf[7], 0.f);
}

// ---------------------------------------------------------------
// Kernel 4: fused gather + SI matmul + nonlinearity + residual.
// One 64-thread block (1 wave) per atom, lane = channel.
// Blocks >= N_ATOMS copy edge0 -> oute.
__global__ __launch_bounds__(64, 2) void atom_fused_kernel(
    const float* __restrict__ node0, const float* __restrict__ node1,
    const float* __restrict__ node2,
    const int* __restrict__ jlist, const int* __restrict__ offsets,
    const float4* __restrict__ ge4, const float* __restrict__ rbf_w,
    const float* __restrict__ si_w0, const float* __restrict__ si_b0,
    const float* __restrict__ si_w1, const float* __restrict__ si_w2,
    const float* __restrict__ nl_w1, const float* __restrict__ nl_b1,
    const float* __restrict__ nl_w2, const float* __restrict__ nl_b2,
    float* __restrict__ out0, float* __restrict__ out1, float* __restrict__ out2,
    const float4* __restrict__ edge0_in, float4* __restrict__ edge0_out)
{
    int n = blockIdx.x;
    int c = threadIdx.x;  // 0..63

    if (n >= N_ATOMS) {
        int cb = n - N_ATOMS;
        size_t base = (size_t)cb * 256;
#pragma unroll
        for (int k = 0; k < 4; ++k)
            edge0_out[base + k * 64 + c] = edge0_in[base + k * 64 + c];
        return;
    }

    __shared__ float abuf[CH][13];

    // rbf mixing weights: wreg[k*NB+b] = rbf_w[k][b][c].
    // The empty-asm "+v" pin forces all 88 values to stay VGPR-resident:
    // without it the allocator rematerializes these loads inside the edge
    // loop (round 3: VGPR=76, ~88 reloads/edge dominated the hot loop).
    float wreg[NK * NB];
#pragma unroll
    for (int kb = 0; kb < NK * NB; ++kb) {
        wreg[kb] = rbf_w[kb * CH + c];
        asm volatile("" : "+v"(wreg[kb]));
    }

    float a0 = 0.f;
    float a1[3] = {0.f, 0.f, 0.f};
    float a2[9] = {0.f, 0.f, 0.f, 0.f, 0.f, 0.f, 0.f, 0.f, 0.f};

    int beg = offsets[n];
    int end = offsets[n + 1];

    // software pipeline: geom + h for edge p, j for edge p+1
    float4 g0, g1v, g2v;
    float h0 = 0.f, h1[3] = {0.f, 0.f, 0.f};
    float h2[9] = {0.f, 0.f, 0.f, 0.f, 0.f, 0.f, 0.f, 0.f, 0.f};
    int jnx = 0;

    if (beg < end) {
        int j = jlist[beg];
        g0 = ge4[beg * 3 + 0];
        g1v = ge4[beg * 3 + 1];
        g2v = ge4[beg * 3 + 2];
        h0 = node0[(size_t)j * CH + c];
#pragma unroll
        for (int x = 0; x < 3; ++x) h1[x] = node1[((size_t)j * CH + c) * 3 + x];
#pragma unroll
        for (int q = 0; q < 9; ++q) h2[q] = node2[((size_t)j * CH + c) * 9 + q];
        jnx = (beg + 1 < end) ? jlist[beg + 1] : 0;
    }

    for (int p = beg; p < end; ++p) {
        float rh[3] = {g0.x, g0.y, g0.z};
        float rbf[NB] = {g0.w, g1v.x, g1v.y, g1v.z, g1v.w, g2v.x, g2v.y, g2v.z};
        float ch0 = h0;
        float ch1[3] = {h1[0], h1[1], h1[2]};
        float ch2[9];
#pragma unroll
        for (int q = 0; q < 9; ++q) ch2[q] = h2[q];

        if (p + 1 < end) {
            int j2 = jnx;
            g0 = ge4[(p + 1) * 3 + 0];
            g1v = ge4[(p + 1) * 3 + 1];
            g2v = ge4[(p + 1) * 3 + 2];
            h0 = node0[(size_t)j2 * CH + c];
#pragma unroll
            for (int x = 0; x < 3; ++x) h1[x] = node1[((size_t)j2 * CH + c) * 3 + x];
#pragma unroll
            for (int q = 0; q < 9; ++q) h2[q] = node2[((size_t)j2 * CH + c) * 9 + q];
            jnx = (p + 2 < end) ? jlist[p + 2] : 0;
        }

        // ---- compute with current edge ----
        float fc[NK];
#pragma unroll
        for (int k = 0; k < NK; ++k) {
            float s = 0.f;
#pragma unroll
            for (int b = 0; b < NB; ++b) s = fmaf(rbf[b], wreg[k * NB + b], s);
            fc[k] = s;
        }

        float u1 = ch1[0] * rh[0] + ch1[1] * rh[1] + ch1[2] * rh[2];
        float v2[3];
#pragma unroll
        for (int x = 0; x < 3; ++x)
            v2[x] = ch2[x * 3] * rh[0] + ch2[x * 3 + 1] * rh[1] + ch2[x * 3 + 2] * rh[2];
        float w2 = v2[0] * rh[0] + v2[1] * rh[1] + v2[2] * rh[2];

        a0 = fmaf(fc[0], ch0, a0);
        a0 = fmaf(fc[4], u1, a0);
        a0 = fmaf(fc[9], w2, a0);

        float c1 = fc[1] * ch0 + fc[6] * u1;
#pragma unroll
        for (int x = 0; x < 3; ++x)
            a1[x] += c1 * rh[x] + fc[3] * ch1[x] + fc[8] * v2[x];

#pragma unroll
        for (int x = 0; x < 3; ++x) {
            float cx = fc[2] * ch0 * rh[x] + fc[5] * ch1[x] + fc[10] * v2[x];
#pragma unroll
            for (int y = 0; y < 3; ++y)
                a2[x * 3 + y] += cx * rh[y] + fc[7] * ch2[x * 3 + y];
        }
    }

    // ---- stage scaled accumulators in LDS, [c][13] (stride 13: conflict-free) ----
    const float SC = 0.1f;  // 1/NORM_FACTOR
    abuf[c][0] = a0 * SC;
#pragma unroll
    for (int x = 0; x < 3; ++x) abuf[c][1 + x] = a1[x] * SC;
#pragma unroll
    for (int q = 0; q < 9; ++q) abuf[c][4 + q] = a2[q] * SC;

    __syncthreads();

    // ---- SI channel mixing (lane = output channel d) ----
    int d = c;
    float s0 = si_b0[d];
    float s1[3] = {0.f, 0.f, 0.f};
    float s2[9] = {0.f, 0.f, 0.f, 0.f, 0.f, 0.f, 0.f, 0.f, 0.f};

#pragma unroll 4
    for (int cc = 0; cc < CH; ++cc) {
        float w0 = si_w0[cc * CH + d];
        float w1 = si_w1[cc * CH + d];
        float w2m = si_w2[cc * CH + d];
        const float* a = abuf[cc];
        s0 = fmaf(a[0], w0, s0);
#pragma unroll
        for (int x = 0; x < 3; ++x) s1[x] = fmaf(a[1 + x], w1, s1[x]);
#pragma unroll
        for (int q = 0; q < 9; ++q) s2[q] = fmaf(a[4 + q], w2m, s2[q]);
    }

    float r0 = s0 / (1.0f + expf(-s0));

    float n1 = sqrtf(s1[0] * s1[0] + s1[1] * s1[1] + s1[2] * s1[2] + 1e-6f);
    float g1 = n1 * nl_w1[d] + nl_b1[d];
    float gate1 = g1 / (1.0f + expf(-g1));

    float n2sq = 1e-6f;
#pragma unroll
    for (int q = 0; q < 9; ++q) n2sq = fmaf(s2[q], s2[q], n2sq);
    float n2 = sqrtf(n2sq);
    float g2 = n2 * nl_w2[d] + nl_b2[d];
    float gate2 = g2 / (1.0f + expf(-g2));

    out0[(size_t)n * CH + d] = node0[(size_t)n * CH + d] + r0;
#pragma unroll
    for (int x = 0; x < 3; ++x)
        out1[((size_t)n * CH + d) * 3 + x] =
            node1[((size_t)n * CH + d) * 3 + x] + s1[x] * gate1;
#pragma unroll
    for (int q = 0; q < 9; ++q)
        out2[((size_t)n * CH + d) * 9 + q] =
            node2[((size_t)n * CH + d) * 9 + q] + s2[q] * gate2;
}

extern "C" void kernel_launch(void* const* d_in, const int* in_sizes, int n_in,
                              void* d_out, int out_size, void* d_ws, size_t ws_size,
                              hipStream_t stream) {
    const float* node0 = (const float*)d_in[0];
    const float* node1 = (const float*)d_in[1];
    const float* node2 = (const float*)d_in[2];
    const float* edge0 = (const float*)d_in[3];
    const float* rij   = (const float*)d_in[4];
    const int*   idx_i = (const int*)d_in[5];
    const int*   idx_j = (const int*)d_in[6];
    const float* rbf_w = (const float*)d_in[7];
    const float* si_w0 = (const float*)d_in[8];
    const float* si_b0 = (const float*)d_in[9];
    const float* si_w1 = (const float*)d_in[10];
    const float* si_w2 = (const float*)d_in[11];
    const float* nl_w1 = (const float*)d_in[12];
    const float* nl_b1 = (const float*)d_in[13];
    const float* nl_w2 = (const float*)d_in[14];
    const float* nl_b2 = (const float*)d_in[15];

    float* out = (float*)d_out;
    float* out0 = out;                                   // [A, C]
    float* out1 = out + (size_t)N_ATOMS * CH;            // [A, C, 3]
    float* out2 = out1 + (size_t)N_ATOMS * CH * 3;       // [A, C, 3, 3]
    float* oute = out2 + (size_t)N_ATOMS * CH * 9;       // [E, C]

    // workspace layout
    char* ws = (char*)d_ws;
    int* counts  = (int*)ws;                              ws += N_ATOMS * sizeof(int);
    int* cursor  = (int*)ws;                              ws += N_ATOMS * sizeof(int);
    int* offsets = (int*)ws;                              ws += (N_ATOMS + 1) * sizeof(int);
    ws = (char*)(((size_t)ws + 15) & ~(size_t)15);
    int* jlist   = (int*)ws;                              ws += N_EDGES * sizeof(int);
    ws = (char*)(((size_t)ws + 15) & ~(size_t)15);
    float4* ge4  = (float4*)ws;                           // 3 * N_EDGES float4

    hipMemsetAsync(counts, 0, N_ATOMS * sizeof(int), stream);

    hist_kernel<<<(N_EDGES + 255) / 256, 256, 0, stream>>>(idx_i, counts);

    scan_kernel<<<1, 1024, 0, stream>>>(counts, offsets, cursor);

    scatter_geom_kernel<<<(N_EDGES + 255) / 256, 256, 0, stream>>>(
        rij, idx_i, idx_j, cursor, jlist, ge4);

    atom_fused_kernel<<<N_ATOMS + COPY_BLOCKS, 64, 0, stream>>>(
        node0, node1, node2, jlist, offsets, ge4, rbf_w,
        si_w0, si_b0, si_w1, si_w2, nl_w1, nl_b1, nl_w2, nl_b2,
        out0, out1, out2,
        (const float4*)edge0, (float4*)oute);
}

// Round 6
// 211.838 us; speedup vs baseline: 1.4727x; 1.4727x over previous
//
#include <hip/hip_runtime.h>
#include <math.h>

#define N_ATOMS 20000
#define N_EDGES 200000
#define CH 64
#define NB 8

#define COPY_F4 (N_EDGES * CH / 4)                 // 3,200,000 float4
#define COPY_PER_BLOCK (192 * 4)                   // 768 float4 per block
#define COPY_BLOCKS ((COPY_F4 + COPY_PER_BLOCK - 1) / COPY_PER_BLOCK)

// ---------------------------------------------------------------
// Kernel 1: histogram of idx_i
__global__ __launch_bounds__(256) void hist_kernel(
    const int* __restrict__ idx_i, int* __restrict__ counts)
{
    int e = blockIdx.x * blockDim.x + threadIdx.x;
    if (e >= N_EDGES) return;
    atomicAdd(&counts[idx_i[e]], 1);
}

// ---------------------------------------------------------------
// Kernel 2: exclusive scan (single 1024-thread block)
__global__ __launch_bounds__(1024) void scan_kernel(
    const int* __restrict__ counts, int* __restrict__ offsets,
    int* __restrict__ cursor)
{
    __shared__ int part[1024];
    const int CHUNK = 20;  // 1024*20 = 20480 >= 20000
    int t = threadIdx.x;
    int beg = t * CHUNK;
    int s = 0;
    for (int k = 0; k < CHUNK; ++k) {
        int idx = beg + k;
        if (idx < N_ATOMS) s += counts[idx];
    }
    part[t] = s;
    __syncthreads();
    for (int off = 1; off < 1024; off <<= 1) {
        int v = (t >= off) ? part[t - off] : 0;
        __syncthreads();
        part[t] += v;
        __syncthreads();
    }
    int run = part[t] - s;
    for (int k = 0; k < CHUNK; ++k) {
        int idx = beg + k;
        if (idx < N_ATOMS) {
            offsets[idx] = run;
            cursor[idx] = run;
            run += counts[idx];
        }
    }
    if (t == 0) offsets[N_ATOMS] = N_EDGES;
}

// ---------------------------------------------------------------
// Kernel 3: scatter into CSR order, computing geometry on the fly
// ge4[p][0..2] = {rh, rbf0..7, pad}; jlist[p] = idx_j[e]
__global__ __launch_bounds__(256) void scatter_geom_kernel(
    const float* __restrict__ rij, const int* __restrict__ idx_i,
    const int* __restrict__ idx_j, int* __restrict__ cursor,
    int* __restrict__ jlist, float4* __restrict__ ge4)
{
    int e = blockIdx.x * blockDim.x + threadIdx.x;
    if (e >= N_EDGES) return;

    float rx = rij[e * 3 + 0];
    float ry = rij[e * 3 + 1];
    float rz = rij[e * 3 + 2];
    float d = sqrtf(rx * rx + ry * ry + rz * rz);
    float inv = 1.0f / (d + 1e-12f);

    float dc = fminf(d, 5.0f);
    float fcut = 0.5f * (cosf(3.14159265358979323846f * dc * 0.2f) + 1.0f);

    float rbf[NB];
#pragma unroll
    for (int b = 0; b < NB; ++b) {
        float mu = (5.0f / 7.0f) * (float)b;
        float t = d - mu;
        rbf[b] = expf(-2.0f * t * t) * fcut;
    }

    int p = atomicAdd(&cursor[idx_i[e]], 1);
    jlist[p] = idx_j[e];
    ge4[p * 3 + 0] = make_float4(rx * inv, ry * inv, rz * inv, rbf[0]);
    ge4[p * 3 + 1] = make_float4(rbf[1], rbf[2], rbf[3], rbf[4]);
    ge4[p * 3 + 2] = make_float4(rbf[5], rbf[6], rbf[7], 0.f);
}

// ---------------------------------------------------------------
// Input-tensor split: wave WID consumes one node tensor, needs <=32
// resident weights/lane (proven non-spilling size), no h duplication.
// WID 0: h0, paths {0,1,2}   WID 1: h1, paths {3,4,5,6}
// WID 2: h2, paths {7,8,9,10}
template<int WID>
__device__ __forceinline__ void accum_loop(
    int n, int c,
    const int* __restrict__ offsets, const int* __restrict__ jlist,
    const float4* __restrict__ ge4,
    const float* __restrict__ node0, const float* __restrict__ node1,
    const float* __restrict__ node2, const float* __restrict__ rbf_w,
    float* __restrict__ pb)   // pbuf slice: [CH][13], stride 13
{
    constexpr int KB = (WID == 0) ? 0 : (WID == 1) ? 3 : 7;
    constexpr int NP = (WID == 0) ? 3 : 4;
    constexpr int NH = (WID == 0) ? 1 : (WID == 1) ? 3 : 9;

    float wp[NP * NB];
#pragma unroll
    for (int pi = 0; pi < NP; ++pi)
#pragma unroll
        for (int b = 0; b < NB; ++b)
            wp[pi * NB + b] = rbf_w[((KB + pi) * NB + b) * CH + c];

    float a0 = 0.f;
    float a1[3] = {0.f, 0.f, 0.f};
    float a2[9] = {0.f, 0.f, 0.f, 0.f, 0.f, 0.f, 0.f, 0.f, 0.f};

    int beg = offsets[n];
    int end = offsets[n + 1];

    float4 g0, g1, g2;
    float h[NH];
    int jn = 0;

    auto LOADH = [&](int j, float* H) {
        size_t b0 = (size_t)j * CH + c;
        if constexpr (WID == 0) {
            H[0] = node0[b0];
        } else if constexpr (WID == 1) {
#pragma unroll
            for (int x = 0; x < 3; ++x) H[x] = node1[b0 * 3 + x];
        } else {
#pragma unroll
            for (int q = 0; q < 9; ++q) H[q] = node2[b0 * 9 + q];
        }
    };

    if (beg < end) {
        g0 = ge4[beg * 3 + 0];
        g1 = ge4[beg * 3 + 1];
        g2 = ge4[beg * 3 + 2];
        LOADH(jlist[beg], h);
        jn = (beg + 1 < end) ? jlist[beg + 1] : 0;
    }

    for (int p = beg; p < end; ++p) {
        float rh[3] = {g0.x, g0.y, g0.z};
        float rbf[NB] = {g0.w, g1.x, g1.y, g1.z, g1.w, g2.x, g2.y, g2.z};
        float hc[NH];
#pragma unroll
        for (int q = 0; q < NH; ++q) hc[q] = h[q];

        if (p + 1 < end) {
            g0 = ge4[(p + 1) * 3 + 0];
            g1 = ge4[(p + 1) * 3 + 1];
            g2 = ge4[(p + 1) * 3 + 2];
            LOADH(jn, h);
            jn = (p + 2 < end) ? jlist[p + 2] : 0;
        }

        float fc[NP];
#pragma unroll
        for (int pi = 0; pi < NP; ++pi) {
            float s = 0.f;
#pragma unroll
            for (int b = 0; b < NB; ++b) s = fmaf(rbf[b], wp[pi * NB + b], s);
            fc[pi] = s;
        }

        if constexpr (WID == 0) {
            // paths 0,1,2 on h0
            a0 = fmaf(fc[0], hc[0], a0);
            float t1 = fc[1] * hc[0];
            float t2 = fc[2] * hc[0];
#pragma unroll
            for (int x = 0; x < 3; ++x) {
                a1[x] = fmaf(t1, rh[x], a1[x]);
                float cx = t2 * rh[x];
#pragma unroll
                for (int y = 0; y < 3; ++y)
                    a2[x * 3 + y] = fmaf(cx, rh[y], a2[x * 3 + y]);
            }
        } else if constexpr (WID == 1) {
            // paths 3,4,5,6 on h1
            float u1 = hc[0] * rh[0] + hc[1] * rh[1] + hc[2] * rh[2];
            a0 = fmaf(fc[1], u1, a0);           // path 4
            float t6 = fc[3] * u1;              // path 6
#pragma unroll
            for (int x = 0; x < 3; ++x) {
                a1[x] += fc[0] * hc[x] + t6 * rh[x];   // paths 3,6
                float cx = fc[2] * hc[x];              // path 5
#pragma unroll
                for (int y = 0; y < 3; ++y)
                    a2[x * 3 + y] = fmaf(cx, rh[y], a2[x * 3 + y]);
            }
        } else {
            // paths 7,8,9,10 on h2
            float v2[3];
#pragma unroll
            for (int x = 0; x < 3; ++x)
                v2[x] = hc[x * 3] * rh[0] + hc[x * 3 + 1] * rh[1] + hc[x * 3 + 2] * rh[2];
            float w2 = v2[0] * rh[0] + v2[1] * rh[1] + v2[2] * rh[2];
            a0 = fmaf(fc[2], w2, a0);           // path 9
#pragma unroll
            for (int x = 0; x < 3; ++x) {
                a1[x] = fmaf(fc[1], v2[x], a1[x]);     // path 8
                float cx = fc[3] * v2[x];              // path 10
#pragma unroll
                for (int y = 0; y < 3; ++y)
                    a2[x * 3 + y] += cx * rh[y] + fc[0] * hc[x * 3 + y];  // 10,7
            }
        }
    }

    const float SC = 0.1f;  // 1/NORM_FACTOR
    pb[c * 13 + 0] = a0 * SC;
#pragma unroll
    for (int x = 0; x < 3; ++x) pb[c * 13 + 1 + x] = a1[x] * SC;
#pragma unroll
    for (int q = 0; q < 9; ++q) pb[c * 13 + 4 + q] = a2[q] * SC;
}

// ---------------------------------------------------------------
// Kernel 4: 192 threads = 3 waves per atom (input-tensor split).
// Blocks >= N_ATOMS copy edge0 -> oute.
__global__ __launch_bounds__(192, 2) void atom_fused_kernel(
    const float* __restrict__ node0, const float* __restrict__ node1,
    const float* __restrict__ node2,
    const int* __restrict__ jlist, const int* __restrict__ offsets,
    const float4* __restrict__ ge4, const float* __restrict__ rbf_w,
    const float* __restrict__ si_w0, const float* __restrict__ si_b0,
    const float* __restrict__ si_w1, const float* __restrict__ si_w2,
    const float* __restrict__ nl_w1, const float* __restrict__ nl_b1,
    const float* __restrict__ nl_w2, const float* __restrict__ nl_b2,
    float* __restrict__ out0, float* __restrict__ out1, float* __restrict__ out2,
    const float4* __restrict__ edge0_in, float4* __restrict__ edge0_out)
{
    int n = blockIdx.x;

    if (n >= N_ATOMS) {
        size_t base = (size_t)(n - N_ATOMS) * COPY_PER_BLOCK;
#pragma unroll
        for (int k = 0; k < 4; ++k) {
            size_t idx = base + (size_t)k * 192 + threadIdx.x;
            if (idx < COPY_F4) edge0_out[idx] = edge0_in[idx];
        }
        return;
    }

    int wv = threadIdx.x >> 6;
    int c = threadIdx.x & 63;

    __shared__ float pbuf[3][CH * 13];   // per-wave partials, stride 13 (conflict-free)
    __shared__ float abuf[CH * 13];      // reduced accumulators
    __shared__ float p2buf[2][9 * CH];   // way-2 mix partials (lane-stride-1)

    if (wv == 0)
        accum_loop<0>(n, c, offsets, jlist, ge4, node0, node1, node2, rbf_w, pbuf[0]);
    else if (wv == 1)
        accum_loop<1>(n, c, offsets, jlist, ge4, node0, node1, node2, rbf_w, pbuf[1]);
    else
        accum_loop<2>(n, c, offsets, jlist, ge4, node0, node1, node2, rbf_w, pbuf[2]);
    __syncthreads();

    // reduce the 3 wave partials: wave wv handles its k-slice for all c
    {
        int k0 = (wv == 0) ? 0 : (wv == 1) ? 5 : 10;
        int k1 = (wv == 0) ? 5 : (wv == 1) ? 10 : 13;
        for (int k = k0; k < k1; ++k)
            abuf[c * 13 + k] = pbuf[0][c * 13 + k] + pbuf[1][c * 13 + k] + pbuf[2][c * 13 + k];
    }
    __syncthreads();

    if (wv == 0) {
        // way0 + way1 mixing, nonlinearity, residual, store
        float s0 = si_b0[c];
        float s1[3] = {0.f, 0.f, 0.f};
        for (int cc = 0; cc < CH; ++cc) {
            const float* a = &abuf[cc * 13];
            float w0 = si_w0[cc * CH + c];
            float w1 = si_w1[cc * CH + c];
            s0 = fmaf(a[0], w0, s0);
#pragma unroll
            for (int x = 0; x < 3; ++x) s1[x] = fmaf(a[1 + x], w1, s1[x]);
        }
        float r0 = s0 / (1.0f + expf(-s0));
        out0[(size_t)n * CH + c] = node0[(size_t)n * CH + c] + r0;

        float n1 = sqrtf(s1[0] * s1[0] + s1[1] * s1[1] + s1[2] * s1[2] + 1e-6f);
        float g1 = n1 * nl_w1[c] + nl_b1[c];
        float gate1 = g1 / (1.0f + expf(-g1));
#pragma unroll
        for (int x = 0; x < 3; ++x)
            out1[((size_t)n * CH + c) * 3 + x] =
                node1[((size_t)n * CH + c) * 3 + x] + s1[x] * gate1;
    } else {
        // way2 mixing split by cc-halves across waves 1 and 2
        float ps2[9] = {0.f, 0.f, 0.f, 0.f, 0.f, 0.f, 0.f, 0.f, 0.f};
        int cc0 = (wv == 1) ? 0 : 32;
        for (int t = 0; t < 32; ++t) {
            int cc = cc0 + t;
            const float* a = &abuf[cc * 13 + 4];
            float w2v = si_w2[cc * CH + c];
#pragma unroll
            for (int q = 0; q < 9; ++q) ps2[q] = fmaf(a[q], w2v, ps2[q]);
        }
#pragma unroll
        for (int q = 0; q < 9; ++q) p2buf[wv - 1][q * CH + c] = ps2[q];
    }
    __syncthreads();

    if (wv == 2) {
        float s2[9];
#pragma unroll
        for (int q = 0; q < 9; ++q) s2[q] = p2buf[0][q * CH + c] + p2buf[1][q * CH + c];

        float n2sq = 1e-6f;
#pragma unroll
        for (int q = 0; q < 9; ++q) n2sq = fmaf(s2[q], s2[q], n2sq);
        float n2 = sqrtf(n2sq);
        float g2 = n2 * nl_w2[c] + nl_b2[c];
        float gate2 = g2 / (1.0f + expf(-g2));
#pragma unroll
        for (int q = 0; q < 9; ++q)
            out2[((size_t)n * CH + c) * 9 + q] =
                node2[((size_t)n * CH + c) * 9 + q] + s2[q] * gate2;
    }
}

extern "C" void kernel_launch(void* const* d_in, const int* in_sizes, int n_in,
                              void* d_out, int out_size, void* d_ws, size_t ws_size,
                              hipStream_t stream) {
    const float* node0 = (const float*)d_in[0];
    const float* node1 = (const float*)d_in[1];
    const float* node2 = (const float*)d_in[2];
    const float* edge0 = (const float*)d_in[3];
    const float* rij   = (const float*)d_in[4];
    const int*   idx_i = (const int*)d_in[5];
    const int*   idx_j = (const int*)d_in[6];
    const float* rbf_w = (const float*)d_in[7];
    const float* si_w0 = (const float*)d_in[8];
    const float* si_b0 = (const float*)d_in[9];
    const float* si_w1 = (const float*)d_in[10];
    const float* si_w2 = (const float*)d_in[11];
    const float* nl_w1 = (const float*)d_in[12];
    const float* nl_b1 = (const float*)d_in[13];
    const float* nl_w2 = (const float*)d_in[14];
    const float* nl_b2 = (const float*)d_in[15];

    float* out = (float*)d_out;
    float* out0 = out;                                   // [A, C]
    float* out1 = out + (size_t)N_ATOMS * CH;            // [A, C, 3]
    float* out2 = out1 + (size_t)N_ATOMS * CH * 3;       // [A, C, 3, 3]
    float* oute = out2 + (size_t)N_ATOMS * CH * 9;       // [E, C]

    // workspace layout
    char* ws = (char*)d_ws;
    int* counts  = (int*)ws;                              ws += N_ATOMS * sizeof(int);
    int* cursor  = (int*)ws;                              ws += N_ATOMS * sizeof(int);
    int* offsets = (int*)ws;                              ws += (N_ATOMS + 1) * sizeof(int);
    ws = (char*)(((size_t)ws + 15) & ~(size_t)15);
    int* jlist   = (int*)ws;                              ws += N_EDGES * sizeof(int);
    ws = (char*)(((size_t)ws + 15) & ~(size_t)15);
    float4* ge4  = (float4*)ws;                           // 3 * N_EDGES float4

    hipMemsetAsync(counts, 0, N_ATOMS * sizeof(int), stream);

    hist_kernel<<<(N_EDGES + 255) / 256, 256, 0, stream>>>(idx_i, counts);

    scan_kernel<<<1, 1024, 0, stream>>>(counts, offsets, cursor);

    scatter_geom_kernel<<<(N_EDGES + 255) / 256, 256, 0, stream>>>(
        rij, idx_i, idx_j, cursor, jlist, ge4);

    atom_fused_kernel<<<N_ATOMS + COPY_BLOCKS, 192, 0, stream>>>(
        node0, node1, node2, jlist, offsets, ge4, rbf_w,
        si_w0, si_b0, si_w1, si_w2, nl_w1, nl_b1, nl_w2, nl_b2,
        out0, out1, out2,
        (const float4*)edge0, (float4*)oute);
}